// Round 1
// baseline (21899.377 us; speedup 1.0000x reference)
//
#include <hip/hip_runtime.h>
#include <math.h>

#define LRELU(v) ((v) > 0.f ? (v) : 0.01f * (v))

// ---------------------------------------------------------------------------
// K1: build full-res image (10,192,192) from input (16,10,48,48)
// full[c][h*4+s1][w*4+s2] = input[s1*4+s2][c][h][w]
// ---------------------------------------------------------------------------
__global__ __launch_bounds__(256) void k_build_full(const float* __restrict__ in,
                                                    float* __restrict__ full) {
    int idx = blockIdx.x * 256 + threadIdx.x;
    if (idx >= 10 * 192 * 192) return;
    int x = idx % 192;
    int rem = idx / 192;
    int y = rem % 192;
    int c = rem / 192;
    int s2 = x & 3, w = x >> 2, s1 = y & 3, h = y >> 2;
    int t = s1 * 4 + s2;
    full[idx] = in[(((t * 10 + c) * 48) + h) * 48 + w];
}

// ---------------------------------------------------------------------------
// K2: conv3x3 pad1 + LeakyReLU.  16x16 pixel tile, BLK_CO output chans/block.
// in: (Cin,H,W)  w: (Cout,Cin,3,3)  out: (Cout,H,W).  H,W divisible by 16.
// ---------------------------------------------------------------------------
template <int BLK_CO>
__global__ __launch_bounds__(256) void k_conv3x3_lrelu(
    const float* __restrict__ in, const float* __restrict__ w,
    const float* __restrict__ bias, float* __restrict__ out, int Cin, int H, int W) {
    __shared__ float tile[18 * 20];
    const int tid = threadIdx.x;
    const int tx = tid & 15, ty = tid >> 4;
    const int x0 = blockIdx.x * 16, y0 = blockIdx.y * 16;
    const int co0 = blockIdx.z * BLK_CO;
    const int HW = H * W;
    float acc[BLK_CO];
#pragma unroll
    for (int i = 0; i < BLK_CO; ++i) acc[i] = 0.f;

    for (int cin = 0; cin < Cin; ++cin) {
        for (int l = tid; l < 324; l += 256) {
            int r = l / 18, c = l - r * 18;
            int gy = y0 - 1 + r, gx = x0 - 1 + c;
            float v = 0.f;
            if (gy >= 0 && gy < H && gx >= 0 && gx < W)
                v = in[(size_t)cin * HW + gy * W + gx];
            tile[r * 20 + c] = v;
        }
        __syncthreads();
        float xv[9];
#pragma unroll
        for (int dy = 0; dy < 3; ++dy)
#pragma unroll
            for (int dx = 0; dx < 3; ++dx)
                xv[dy * 3 + dx] = tile[(ty + dy) * 20 + tx + dx];
        const float* wp = w + ((size_t)co0 * Cin + cin) * 9;  // block-uniform
#pragma unroll
        for (int q = 0; q < 9; ++q) {
            float xq = xv[q];
#pragma unroll
            for (int co = 0; co < BLK_CO; ++co)
                acc[co] += xq * wp[(size_t)co * Cin * 9 + q];
        }
        __syncthreads();
    }
    int oy = y0 + ty, ox = x0 + tx;
#pragma unroll
    for (int co = 0; co < BLK_CO; ++co) {
        float v = acc[co] + bias[co0 + co];
        out[(size_t)(co0 + co) * HW + oy * W + ox] = LRELU(v);
    }
}

// ---------------------------------------------------------------------------
// K3: conv 4x4 stride 4 (non-overlapping) + LeakyReLU.
// in: (100,192,192)  w: (1024,100,4,4)  out: (1024,48,48)
// ---------------------------------------------------------------------------
__global__ __launch_bounds__(256) void k_conv4x4s4_lrelu(
    const float* __restrict__ in, const float* __restrict__ w,
    const float* __restrict__ bias, float* __restrict__ out) {
    __shared__ __align__(16) float tile[64 * 68];
    const int tid = threadIdx.x;
    const int tx = tid & 15, ty = tid >> 4;
    const int ox0 = blockIdx.x * 16, oy0 = blockIdx.y * 16;
    const int co0 = blockIdx.z * 16;
    float acc[16];
#pragma unroll
    for (int i = 0; i < 16; ++i) acc[i] = 0.f;

    for (int cin = 0; cin < 100; ++cin) {
        for (int l = tid; l < 4096; l += 256) {
            int r = l >> 6, c = l & 63;
            tile[r * 68 + c] = in[(size_t)cin * 36864 + (oy0 * 4 + r) * 192 + ox0 * 4 + c];
        }
        __syncthreads();
        float xv[16];
#pragma unroll
        for (int dy = 0; dy < 4; ++dy) {
            float4 v = *(const float4*)&tile[(ty * 4 + dy) * 68 + tx * 4];
            xv[dy * 4 + 0] = v.x; xv[dy * 4 + 1] = v.y;
            xv[dy * 4 + 2] = v.z; xv[dy * 4 + 3] = v.w;
        }
        const float* wp = w + ((size_t)co0 * 100 + cin) * 16;  // block-uniform
#pragma unroll
        for (int q = 0; q < 16; ++q) {
            float xq = xv[q];
#pragma unroll
            for (int co = 0; co < 16; ++co)
                acc[co] += xq * wp[(size_t)co * 1600 + q];
        }
        __syncthreads();
    }
#pragma unroll
    for (int co = 0; co < 16; ++co) {
        float v = acc[co] + bias[co0 + co];
        out[(size_t)(co0 + co) * 2304 + (oy0 + ty) * 48 + ox0 + tx] = LRELU(v);
    }
}

// ---------------------------------------------------------------------------
// K4: SGEMM out = act(A(MxK) * B(KxN) + bias[m]).  64x64 tile, 4x4 microtile.
// act: 0 = LeakyReLU, 1 = tanh.  transpose_out: store out[n*M+m] (via LDS).
// M%64==0, N%64==0, K%16==0.
// ---------------------------------------------------------------------------
__global__ __launch_bounds__(256) void k_gemm_bias_act(
    const float* __restrict__ A, const float* __restrict__ B,
    const float* __restrict__ bias, float* __restrict__ out,
    int M, int K, int N, int act, int transpose_out) {
    __shared__ __align__(16) float smem[64 * 66];
    float* As = smem;            // [16][68]
    float* Bs = smem + 16 * 68;  // [16][68]
    const int tid = threadIdx.x;
    const int tx = tid & 15, ty = tid >> 4;
    const int n0 = blockIdx.x * 64, m0 = blockIdx.y * 64;
    float acc[4][4];
#pragma unroll
    for (int i = 0; i < 4; ++i)
#pragma unroll
        for (int j = 0; j < 4; ++j) acc[i][j] = 0.f;

    const int a_m = tid >> 2;
    const int a_k = (tid & 3) << 2;
    const int b_k = tid >> 4;
    const int b_n = (tid & 15) << 2;
    const float* Ap = A + (size_t)(m0 + a_m) * K + a_k;
    const float* Bp = B + (size_t)b_k * N + n0 + b_n;

    for (int k0 = 0; k0 < K; k0 += 16) {
        float4 av = *(const float4*)(Ap + k0);
        float4 bv = *(const float4*)(Bp + (size_t)k0 * N);
        As[(a_k + 0) * 68 + a_m] = av.x;
        As[(a_k + 1) * 68 + a_m] = av.y;
        As[(a_k + 2) * 68 + a_m] = av.z;
        As[(a_k + 3) * 68 + a_m] = av.w;
        *(float4*)&Bs[b_k * 68 + b_n] = bv;
        __syncthreads();
#pragma unroll
        for (int kk = 0; kk < 16; ++kk) {
            float4 a = *(const float4*)&As[kk * 68 + ty * 4];
            float4 b = *(const float4*)&Bs[kk * 68 + tx * 4];
            acc[0][0] += a.x * b.x; acc[0][1] += a.x * b.y; acc[0][2] += a.x * b.z; acc[0][3] += a.x * b.w;
            acc[1][0] += a.y * b.x; acc[1][1] += a.y * b.y; acc[1][2] += a.y * b.z; acc[1][3] += a.y * b.w;
            acc[2][0] += a.z * b.x; acc[2][1] += a.z * b.y; acc[2][2] += a.z * b.z; acc[2][3] += a.z * b.w;
            acc[3][0] += a.w * b.x; acc[3][1] += a.w * b.y; acc[3][2] += a.w * b.z; acc[3][3] += a.w * b.w;
        }
        __syncthreads();
    }
    // bias + activation
#pragma unroll
    for (int i = 0; i < 4; ++i) {
        float bi = bias[m0 + ty * 4 + i];
#pragma unroll
        for (int j = 0; j < 4; ++j) {
            float v = acc[i][j] + bi;
            acc[i][j] = act ? tanhf(v) : LRELU(v);
        }
    }
    if (!transpose_out) {
#pragma unroll
        for (int i = 0; i < 4; ++i) {
            float4 r = make_float4(acc[i][0], acc[i][1], acc[i][2], acc[i][3]);
            *(float4*)&out[(size_t)(m0 + ty * 4 + i) * N + n0 + tx * 4] = r;
        }
    } else {
        // stage as [n_local][m_local] for coalesced transposed writes
#pragma unroll
        for (int i = 0; i < 4; ++i)
#pragma unroll
            for (int j = 0; j < 4; ++j)
                smem[(tx * 4 + j) * 66 + ty * 4 + i] = acc[i][j];
        __syncthreads();
        for (int l = tid; l < 4096; l += 256) {
            int nl = l >> 6, ml = l & 63;
            out[(size_t)(n0 + nl) * M + m0 + ml] = smem[nl * 66 + ml];
        }
    }
}

// ---------------------------------------------------------------------------
// K5: per-pixel normal equations + solve.  One block (256 thr) per pixel.
// WmT: [2304][12544] pixel-major tanh(Wmap).  design: (16,7,48,48).
// input: (16,10,48,48).  out: (16,3,48,48) flat.
// ---------------------------------------------------------------------------
__global__ __launch_bounds__(256) void k_solve(const float* __restrict__ WmT,
                                               const float* __restrict__ design,
                                               const float* __restrict__ input,
                                               float* __restrict__ out) {
    const int p = blockIdx.x;  // 0..2303
    const int h = p / 48, wpx = p % 48;
    const int tid = threadIdx.x;
    __shared__ float Msh[16 * 17];
    __shared__ float Gsh[16 * 17];
    __shared__ float Xsh[16 * 8];
    __shared__ float Ysh[16 * 4];
    __shared__ float XTWsh[7 * 17];
    __shared__ float Aacc[49];
    __shared__ float Bacc[21];
    __shared__ float parash[21];

    if (tid < 49) Aacc[tid] = 0.f;
    if (tid >= 64 && tid < 85) Bacc[tid - 64] = 0.f;
    __syncthreads();

    const float* wrow = WmT + (size_t)p * 12544;
    for (int ni = 0; ni < 49; ++ni) {
        {  // load M (16x16), coalesced
            int t1 = tid >> 4, t2 = tid & 15;
            Msh[t1 * 17 + t2] = wrow[ni * 256 + tid];
        }
        int sy = h + ni / 7 - 3, sx = wpx + ni % 7 - 3;
        bool inb = (sy >= 0 && sy < 48 && sx >= 0 && sx < 48);
        if (tid < 112) {  // X[t][c] = design[t][c][sy][sx]
            int t = tid / 7, c = tid - t * 7;
            Xsh[t * 8 + c] = inb ? design[(size_t)(t * 7 + c) * 2304 + sy * 48 + sx] : 0.f;
        } else if (tid >= 128 && tid < 176) {  // Y[t][r] = input[t][r][sy][sx]
            int l = tid - 128;
            int t = l / 3, r = l - t * 3;
            Ysh[t * 4 + r] = inb ? input[(size_t)(t * 10 + r) * 2304 + sy * 48 + sx] : 0.f;
        }
        __syncthreads();
        {  // G = M M^T + I
            int t1 = tid >> 4, t2 = tid & 15;
            float s = (t1 == t2) ? 1.f : 0.f;
#pragma unroll
            for (int k = 0; k < 16; ++k) s += Msh[t1 * 17 + k] * Msh[t2 * 17 + k];
            Gsh[t1 * 17 + t2] = s;
        }
        __syncthreads();
        if (tid < 112) {  // XTW[c][t2] = sum_t1 X[t1][c] G[t1][t2]
            int c = tid >> 4, t2 = tid & 15;
            float s = 0.f;
#pragma unroll
            for (int t1 = 0; t1 < 16; ++t1) s += Xsh[t1 * 8 + c] * Gsh[t1 * 17 + t2];
            XTWsh[c * 17 + t2] = s;
        }
        __syncthreads();
        if (tid < 49) {  // A += XTW @ X
            int c1 = tid / 7, c2 = tid - c1 * 7;
            float s = 0.f;
#pragma unroll
            for (int t = 0; t < 16; ++t) s += XTWsh[c1 * 17 + t] * Xsh[t * 8 + c2];
            Aacc[tid] += s;
        } else if (tid >= 64 && tid < 85) {  // Bv += XTW @ Y
            int l = tid - 64;
            int c = l / 3, r = l - c * 3;
            float s = 0.f;
#pragma unroll
            for (int t = 0; t < 16; ++t) s += XTWsh[c * 17 + t] * Ysh[t * 4 + r];
            Bacc[l] += s;
        }
        __syncthreads();
    }

    if (tid == 0) {  // Gauss-Jordan on [A+eps*I | Bv]  (A is SPD -> no pivoting)
        float Mg[7][10];
#pragma unroll
        for (int i = 0; i < 7; ++i) {
#pragma unroll
            for (int j = 0; j < 7; ++j) Mg[i][j] = Aacc[i * 7 + j] + ((i == j) ? 0.01f : 0.f);
#pragma unroll
            for (int r = 0; r < 3; ++r) Mg[i][7 + r] = Bacc[i * 3 + r];
        }
#pragma unroll
        for (int kk = 0; kk < 7; ++kk) {
            float inv = 1.f / Mg[kk][kk];
#pragma unroll
            for (int j = 0; j < 10; ++j) Mg[kk][j] *= inv;
#pragma unroll
            for (int i = 0; i < 7; ++i) {
                if (i == kk) continue;
                float f = Mg[i][kk];
#pragma unroll
                for (int j = 0; j < 10; ++j) Mg[i][j] -= f * Mg[kk][j];
            }
        }
#pragma unroll
        for (int c = 0; c < 7; ++c)
#pragma unroll
            for (int r = 0; r < 3; ++r) parash[c * 3 + r] = Mg[c][7 + r];
    }
    __syncthreads();

    if (tid < 48) {  // out[t][r] = sum_c design[t][c][h][w] * para[c][r]
        int t = tid / 3, r = tid - t * 3;
        float s = 0.f;
#pragma unroll
        for (int c = 0; c < 7; ++c)
            s += design[(size_t)(t * 7 + c) * 2304 + p] * parash[c * 3 + r];
        out[(size_t)tid * 2304 + p] = s;
    }
}

// ---------------------------------------------------------------------------
extern "C" void kernel_launch(void* const* d_in, const int* in_sizes, int n_in,
                              void* d_out, int out_size, void* d_ws, size_t ws_size,
                              hipStream_t stream) {
    const float* input   = (const float*)d_in[0];
    const float* design  = (const float*)d_in[1];
    const float* fw0     = (const float*)d_in[2];
    const float* fb0     = (const float*)d_in[3];
    const float* fw_rest = (const float*)d_in[4];
    const float* fb_rest = (const float*)d_in[5];
    const float* ww0     = (const float*)d_in[6];
    const float* wb0     = (const float*)d_in[7];
    const float* ww_mid  = (const float*)d_in[8];
    const float* wb_mid  = (const float*)d_in[9];
    const float* ww1     = (const float*)d_in[10];
    const float* wb1     = (const float*)d_in[11];
    const float* ww2     = (const float*)d_in[12];
    const float* wb2     = (const float*)d_in[13];
    float* out = (float*)d_out;
    float* ws = (float*)d_ws;

    // workspace layout (floats), with aliasing:
    //   g1  : [0, 14450688)                      live GEMM1 -> GEMM2
    //   WmT : [14450688, 43352064)               written by GEMM2, read by solve
    //   full/fA/fB/gA/gB alias inside WmT region (all dead before GEMM2 writes)
    float* g1   = ws;
    float* WmT  = ws + 14450688;
    float* full = ws + 14450688;
    float* fA   = ws + 14450688 + 368640;
    float* fB   = fA + 3686400;
    float* gA   = fB + 3686400;
    float* gB   = gA + 2359296;

    k_build_full<<<1440, 256, 0, stream>>>(input, full);

    // feature network: conv0 (10->100) + 13x (100->100) at 192x192
    k_conv3x3_lrelu<25><<<dim3(12, 12, 4), 256, 0, stream>>>(full, fw0, fb0, fA, 10, 192, 192);
    float* src = fA;
    float* dst = fB;
    for (int i = 0; i < 13; ++i) {
        k_conv3x3_lrelu<25><<<dim3(12, 12, 4), 256, 0, stream>>>(
            src, fw_rest + (size_t)i * 90000, fb_rest + i * 100, dst, 100, 192, 192);
        float* t = src; src = dst; dst = t;
    }

    // weight network
    k_conv4x4s4_lrelu<<<dim3(3, 3, 64), 256, 0, stream>>>(src, ww0, wb0, gA);
    float* gs = gA;
    float* gd = gB;
    for (int i = 0; i < 3; ++i) {
        k_conv3x3_lrelu<16><<<dim3(3, 3, 64), 256, 0, stream>>>(
            gs, ww_mid + (size_t)i * 9437184, wb_mid + i * 1024, gd, 1024, 48, 48);
        float* t = gs; gs = gd; gd = t;
    }
    // gs == gB here (final g), disjoint from g1
    k_gemm_bias_act<<<dim3(36, 98), 256, 0, stream>>>(ww1, gs, wb1, g1, 6272, 1024, 2304, 0, 0);
    k_gemm_bias_act<<<dim3(36, 196), 256, 0, stream>>>(ww2, g1, wb2, WmT, 12544, 6272, 2304, 1, 1);

    k_solve<<<2304, 256, 0, stream>>>(WmT, design, input, out);
}

// Round 2
// 3374.602 us; speedup vs baseline: 6.4895x; 6.4895x over previous
//
#include <hip/hip_runtime.h>
#include <math.h>

#define LRELU(v) ((v) > 0.f ? (v) : 0.01f * (v))

typedef __attribute__((ext_vector_type(8))) short bf8v;   // 8 x bf16 (4 VGPRs)
typedef __attribute__((ext_vector_type(4))) float f4v;    // MFMA accumulator

// fp32 -> bf16 round-to-nearest-even
static __device__ __forceinline__ unsigned short f2b(float f) {
    unsigned int u = __float_as_uint(f);
    unsigned int r = (u + 0x7fffu + ((u >> 16) & 1u)) >> 16;
    return (unsigned short)r;
}

// ---------------------------------------------------------------------------
// K1: build full-res image, pixel-major bf16 [36864][10]
// full0[(Y*192+X)*10 + c] = input[t=(Y&3)*4+(X&3)][c][Y>>2][X>>2]
// ---------------------------------------------------------------------------
__global__ __launch_bounds__(256) void k_build_full(const float* __restrict__ in,
                                                    unsigned short* __restrict__ full0) {
    int idx = blockIdx.x * 256 + threadIdx.x;
    if (idx >= 368640) return;
    int c = idx % 10, pix = idx / 10;
    int X = pix % 192, Y = pix / 192;
    int t = (Y & 3) * 4 + (X & 3);
    int h = Y >> 2, w = X >> 2;
    full0[idx] = f2b(in[(((t * 10 + c) * 48) + h) * 48 + w]);
}

// ---------------------------------------------------------------------------
// K2: weight convert+permute fp32 -> bf16.  src (Mv, C, Q) row-major,
// dst [gridDim.x(Mp)][Kp] with kp = q*C + c; zero pad (m>=Mv or kp>=C*Q).
// ---------------------------------------------------------------------------
template <int C, int Q>
__global__ __launch_bounds__(256) void k_wcvt(const float* __restrict__ src,
                                              unsigned short* __restrict__ dst,
                                              int Mv, int Kp) {
    int m = blockIdx.x;
    for (int kp = threadIdx.x; kp < Kp; kp += 256) {
        float v = 0.f;
        if (m < Mv && kp < C * Q) {
            int qq = kp / C, c = kp - qq * C;
            v = src[((size_t)m * C + c) * Q + qq];
        }
        dst[(size_t)m * Kp + kp] = f2b(v);
    }
}

// ---------------------------------------------------------------------------
// K3: im2col 3x3 pad1, pixel-major bf16 src [H*W][C] -> dst [H*W][Kp],
// kp = q*C + c, q = (dy+1)*3 + (dx+1).  Zero for OOB / kp >= 9C.
// ---------------------------------------------------------------------------
template <int C>
__global__ __launch_bounds__(256) void k_im2col3(const unsigned short* __restrict__ src,
                                                 unsigned short* __restrict__ dst,
                                                 int W, int H, int Kp) {
    int p = blockIdx.x;
    int x = p % W, y = p / W;
    for (int kp = threadIdx.x; kp < Kp; kp += 256) {
        unsigned short v = 0;
        if (kp < 9 * C) {
            int qq = kp / C, c = kp - qq * C;
            int yy = y + qq / 3 - 1, xx = x + qq % 3 - 1;
            if (yy >= 0 && yy < H && xx >= 0 && xx < W)
                v = src[(size_t)(yy * W + xx) * C + c];
        }
        dst[(size_t)p * Kp + kp] = v;
    }
}

// ---------------------------------------------------------------------------
// K4: im2col 4x4 stride4 for conv4x4s4: src [36864][100] -> dst [2304][1600],
// kp = (dy*4+dx)*100 + c
// ---------------------------------------------------------------------------
__global__ __launch_bounds__(256) void k_im2col4(const unsigned short* __restrict__ src,
                                                 unsigned short* __restrict__ dst) {
    int p = blockIdx.x;  // 0..2303
    int x = p % 48, y = p / 48;
    for (int kp = threadIdx.x; kp < 1600; kp += 256) {
        int qq = kp / 100, c = kp - qq * 100;
        int yy = y * 4 + (qq >> 2), xx = x * 4 + (qq & 3);
        dst[(size_t)p * 1600 + kp] = src[(size_t)(yy * 192 + xx) * 100 + c];
    }
}

// ---------------------------------------------------------------------------
// K5: MFMA GEMM.  D[m][n] = act(A[m][k] * Bt[n][k] + bias[m]), stored
// TRANSPOSED: out[n][m] (row stride ldout).  A bf16 [>=128*gy][K] or fp32
// (AF32, converted during staging).  Bt bf16 [N][K].  K % 32 == 0.
// Block: 256 thr = 4 waves, tile 128(m) x 128(n), wave = 64x64 = 4x4 MFMA.
// mfma_f32_16x16x32_bf16:  A-frag lane l: A[m=l&15][k=(l>>4)*8+j]
//                          B-frag lane l: B[k=(l>>4)*8+j][n=l&15]
//                          D lane l reg r: D[row=(l>>4)*4+r][col=l&15]
// ---------------------------------------------------------------------------
template <int ACT, int OF32, int AF32>
__global__ __launch_bounds__(256) void k_gemm(
    const void* __restrict__ Ain, const unsigned short* __restrict__ Bt,
    const float* __restrict__ bias, void* __restrict__ outv,
    int K, int Mv, int ldout) {
    __shared__ __align__(16) unsigned short As[128 * 40];  // +8 pad: bank-safe
    __shared__ __align__(16) unsigned short Bs[128 * 40];
    const int tid = threadIdx.x;
    const int lane = tid & 63;
    const int w = tid >> 6;
    const int wm = w >> 1, wn = w & 1;
    const int q = lane >> 4, ln = lane & 15;
    const int m0 = blockIdx.y * 128, n0 = blockIdx.x * 128;

    f4v acc[4][4];
#pragma unroll
    for (int i = 0; i < 4; ++i)
#pragma unroll
        for (int j = 0; j < 4; ++j) acc[i][j] = (f4v){0.f, 0.f, 0.f, 0.f};

    // staging chunk mapping (bf16): chunk c -> row c>>2, k8 = (c&3)*8
    const int br0 = tid >> 2, bk0 = (tid & 3) << 3;  // chunk tid
    const int br1 = br0 + 64;                        // chunk tid+256
    const int bl0 = br0 * 40 + bk0, bl1 = br1 * 40 + bk0;
    const unsigned short* pB0 = Bt + (size_t)(n0 + br0) * K + bk0;
    const unsigned short* pB1 = Bt + (size_t)(n0 + br1) * K + bk0;

    const unsigned short* Ab = (const unsigned short*)Ain;
    const float* Af = (const float*)Ain;
    const unsigned short* pA0 = Ab + (size_t)(m0 + br0) * K + bk0;
    const unsigned short* pA1 = Ab + (size_t)(m0 + br1) * K + bk0;
    // fp32 staging: chunk cc=tid+j*256 -> row (cc>>3) = fr + j*32, k4=(tid&7)*4
    const int fr = tid >> 3, fk = (tid & 7) << 2;
    const float* pF = Af + (size_t)(m0 + fr) * K + fk;

    for (int k0 = 0; k0 < K; k0 += 32) {
        if (AF32) {
#pragma unroll
            for (int jj = 0; jj < 4; ++jj) {
                float4 v = *(const float4*)(pF + (size_t)jj * 32 * K + k0);
                unsigned int lo = ((unsigned)f2b(v.y) << 16) | f2b(v.x);
                unsigned int hi = ((unsigned)f2b(v.w) << 16) | f2b(v.z);
                *(uint2*)&As[(fr + jj * 32) * 40 + fk] = make_uint2(lo, hi);
            }
        } else {
            uint4 a0 = *(const uint4*)(pA0 + k0);
            uint4 a1 = *(const uint4*)(pA1 + k0);
            *(uint4*)&As[bl0] = a0;
            *(uint4*)&As[bl1] = a1;
        }
        uint4 b0 = *(const uint4*)(pB0 + k0);
        uint4 b1 = *(const uint4*)(pB1 + k0);
        *(uint4*)&Bs[bl0] = b0;
        *(uint4*)&Bs[bl1] = b1;
        __syncthreads();
        const unsigned short* Ap2 = &As[(wm * 64 + ln) * 40 + q * 8];
        const unsigned short* Bp2 = &Bs[(wn * 64 + ln) * 40 + q * 8];
        bf8v af[4], bfv[4];
#pragma unroll
        for (int i = 0; i < 4; ++i) af[i] = *(const bf8v*)(Ap2 + i * 640);
#pragma unroll
        for (int j = 0; j < 4; ++j) bfv[j] = *(const bf8v*)(Bp2 + j * 640);
#pragma unroll
        for (int i = 0; i < 4; ++i)
#pragma unroll
            for (int j = 0; j < 4; ++j)
                acc[i][j] = __builtin_amdgcn_mfma_f32_16x16x32_bf16(af[i], bfv[j], acc[i][j], 0, 0, 0);
        __syncthreads();
    }

    // transposed epilogue: per-wave 16x17 LDS tile (intra-wave only)
    float* tb = ((float*)As) + w * 288;
#pragma unroll
    for (int i = 0; i < 4; ++i) {
        const int mbase = m0 + wm * 64 + i * 16;
        float bi[4];
#pragma unroll
        for (int r = 0; r < 4; ++r) {
            int mm = mbase + q * 4 + r;
            bi[r] = (mm < Mv) ? bias[mm] : 0.f;
        }
#pragma unroll
        for (int j = 0; j < 4; ++j) {
            const int nbase = n0 + wn * 64 + j * 16;
#pragma unroll
            for (int r = 0; r < 4; ++r) {
                float v = acc[i][j][r] + bi[r];
                v = ACT ? tanhf(v) : LRELU(v);
                tb[ln * 17 + q * 4 + r] = v;  // tb[col][row] = D[row][col]
            }
#pragma unroll
            for (int r = 0; r < 4; ++r) {
                float v = tb[(q * 4 + r) * 17 + ln];  // = D[row=ln][col=q*4+r]
                size_t n = nbase + q * 4 + r;
                int m = mbase + ln;
                if (m < Mv) {
                    if (OF32) ((float*)outv)[n * (size_t)ldout + m] = v;
                    else ((unsigned short*)outv)[n * (size_t)ldout + m] = f2b(v);
                }
            }
        }
    }
}

// ---------------------------------------------------------------------------
// K6: per-pixel normal equations + solve (verified round-0 kernel, unchanged)
// ---------------------------------------------------------------------------
__global__ __launch_bounds__(256) void k_solve(const float* __restrict__ WmT,
                                               const float* __restrict__ design,
                                               const float* __restrict__ input,
                                               float* __restrict__ out) {
    const int p = blockIdx.x;  // 0..2303
    const int h = p / 48, wpx = p % 48;
    const int tid = threadIdx.x;
    __shared__ float Msh[16 * 17];
    __shared__ float Gsh[16 * 17];
    __shared__ float Xsh[16 * 8];
    __shared__ float Ysh[16 * 4];
    __shared__ float XTWsh[7 * 17];
    __shared__ float Aacc[49];
    __shared__ float Bacc[21];
    __shared__ float parash[21];

    if (tid < 49) Aacc[tid] = 0.f;
    if (tid >= 64 && tid < 85) Bacc[tid - 64] = 0.f;
    __syncthreads();

    const float* wrow = WmT + (size_t)p * 12544;
    for (int ni = 0; ni < 49; ++ni) {
        {
            int t1 = tid >> 4, t2 = tid & 15;
            Msh[t1 * 17 + t2] = wrow[ni * 256 + tid];
        }
        int sy = h + ni / 7 - 3, sx = wpx + ni % 7 - 3;
        bool inb = (sy >= 0 && sy < 48 && sx >= 0 && sx < 48);
        if (tid < 112) {
            int t = tid / 7, c = tid - t * 7;
            Xsh[t * 8 + c] = inb ? design[(size_t)(t * 7 + c) * 2304 + sy * 48 + sx] : 0.f;
        } else if (tid >= 128 && tid < 176) {
            int l = tid - 128;
            int t = l / 3, r = l - t * 3;
            Ysh[t * 4 + r] = inb ? input[(size_t)(t * 10 + r) * 2304 + sy * 48 + sx] : 0.f;
        }
        __syncthreads();
        {
            int t1 = tid >> 4, t2 = tid & 15;
            float s = (t1 == t2) ? 1.f : 0.f;
#pragma unroll
            for (int k = 0; k < 16; ++k) s += Msh[t1 * 17 + k] * Msh[t2 * 17 + k];
            Gsh[t1 * 17 + t2] = s;
        }
        __syncthreads();
        if (tid < 112) {
            int c = tid >> 4, t2 = tid & 15;
            float s = 0.f;
#pragma unroll
            for (int t1 = 0; t1 < 16; ++t1) s += Xsh[t1 * 8 + c] * Gsh[t1 * 17 + t2];
            XTWsh[c * 17 + t2] = s;
        }
        __syncthreads();
        if (tid < 49) {
            int c1 = tid / 7, c2 = tid - c1 * 7;
            float s = 0.f;
#pragma unroll
            for (int t = 0; t < 16; ++t) s += XTWsh[c1 * 17 + t] * Xsh[t * 8 + c2];
            Aacc[tid] += s;
        } else if (tid >= 64 && tid < 85) {
            int l = tid - 64;
            int c = l / 3, r = l - c * 3;
            float s = 0.f;
#pragma unroll
            for (int t = 0; t < 16; ++t) s += XTWsh[c * 17 + t] * Ysh[t * 4 + r];
            Bacc[l] += s;
        }
        __syncthreads();
    }

    if (tid == 0) {
        float Mg[7][10];
#pragma unroll
        for (int i = 0; i < 7; ++i) {
#pragma unroll
            for (int j = 0; j < 7; ++j) Mg[i][j] = Aacc[i * 7 + j] + ((i == j) ? 0.01f : 0.f);
#pragma unroll
            for (int r = 0; r < 3; ++r) Mg[i][7 + r] = Bacc[i * 3 + r];
        }
#pragma unroll
        for (int kk = 0; kk < 7; ++kk) {
            float inv = 1.f / Mg[kk][kk];
#pragma unroll
            for (int j = 0; j < 10; ++j) Mg[kk][j] *= inv;
#pragma unroll
            for (int i = 0; i < 7; ++i) {
                if (i == kk) continue;
                float f = Mg[i][kk];
#pragma unroll
                for (int j = 0; j < 10; ++j) Mg[i][j] -= f * Mg[kk][j];
            }
        }
#pragma unroll
        for (int c = 0; c < 7; ++c)
#pragma unroll
            for (int r = 0; r < 3; ++r) parash[c * 3 + r] = Mg[c][7 + r];
    }
    __syncthreads();

    if (tid < 48) {
        int t = tid / 3, r = tid - t * 3;
        float s = 0.f;
#pragma unroll
        for (int c = 0; c < 7; ++c)
            s += design[(size_t)(t * 7 + c) * 2304 + p] * parash[c * 3 + r];
        out[(size_t)tid * 2304 + p] = s;
    }
}

// ---------------------------------------------------------------------------
extern "C" void kernel_launch(void* const* d_in, const int* in_sizes, int n_in,
                              void* d_out, int out_size, void* d_ws, size_t ws_size,
                              hipStream_t stream) {
    const float* input   = (const float*)d_in[0];
    const float* design  = (const float*)d_in[1];
    const float* fw0     = (const float*)d_in[2];
    const float* fb0     = (const float*)d_in[3];
    const float* fw_rest = (const float*)d_in[4];
    const float* fb_rest = (const float*)d_in[5];
    const float* ww0     = (const float*)d_in[6];
    const float* wb0     = (const float*)d_in[7];
    const float* ww_mid  = (const float*)d_in[8];
    const float* wb_mid  = (const float*)d_in[9];
    const float* ww1     = (const float*)d_in[10];
    const float* wb1     = (const float*)d_in[11];
    const float* ww2     = (const float*)d_in[12];
    const float* wb2     = (const float*)d_in[13];
    float* out = (float*)d_out;
    float* ws = (float*)d_ws;

    // ---- workspace layout (float units; region A [0,28901376) aliases WmT) --
    float* WmT = ws;                                     // fp32 [2304][12544]
    unsigned short* colF  = (unsigned short*)(ws);                  // <=17,104,896 f
    unsigned short* actA  = (unsigned short*)(ws + 17104896);       // 1,843,200 f
    unsigned short* actB  = (unsigned short*)(ws + 18948096);       // 1,843,200 f
    unsigned short* full0 = (unsigned short*)(ws + 20791296);       //   184,320 f
    unsigned short* fw0b  = (unsigned short*)(ws + 20975616);       //     6,144 f
    unsigned short* fwrb  = (unsigned short*)(ws + 20981760);       //   772,096 f (13 x 59392)
    unsigned short* ww0b  = (unsigned short*)(ws + 21753856);       //   819,200 f
    unsigned short* wmb   = (unsigned short*)(ws + 22573056);       // 4,718,592 f (ends 27,291,648)
    unsigned short* g1    = (unsigned short*)(ws + 28901376);       // 7,225,344 f
    unsigned short* ww1b  = (unsigned short*)(ws + 36126720);       // 3,211,264 f (ends 39,337,984)

    // ---- weight conversions (except ww_mid: per-layer, and ww2: on-the-fly)
    k_wcvt<10, 9><<<128, 256, 0, stream>>>(fw0, fw0b, 100, 96);
    for (int i = 0; i < 13; ++i)
        k_wcvt<100, 9><<<128, 256, 0, stream>>>(fw_rest + (size_t)i * 90000,
                                                fwrb + (size_t)i * 118784, 100, 928);
    k_wcvt<100, 16><<<1024, 256, 0, stream>>>(ww0, ww0b, 1024, 1600);
    k_wcvt<1024, 1><<<6272, 256, 0, stream>>>(ww1, ww1b, 6272, 1024);

    // ---- feature network: 14 x (im2col + GEMM), pixel-major [36864][100]
    k_build_full<<<1440, 256, 0, stream>>>(input, full0);
    k_im2col3<10><<<36864, 256, 0, stream>>>(full0, colF, 192, 192, 96);
    k_gemm<0, 0, 0><<<dim3(288, 1), 256, 0, stream>>>(fw0b, colF, fb0, actA, 96, 100, 100);
    unsigned short* src = actA;
    unsigned short* dst = actB;
    for (int i = 0; i < 13; ++i) {
        k_im2col3<100><<<36864, 256, 0, stream>>>(src, colF, 192, 192, 928);
        k_gemm<0, 0, 0><<<dim3(288, 1), 256, 0, stream>>>(
            fwrb + (size_t)i * 118784, colF, fb_rest + i * 100, dst, 928, 100, 100);
        unsigned short* t = src; src = dst; dst = t;
    }
    // src == actB (final feature map)

    // ---- weight network head: conv4x4 s4 -> [2304][1024]
    unsigned short* col4 = colF;
    k_im2col4<<<2304, 256, 0, stream>>>(src, col4);
    unsigned short* gA = actA;  // [2304][1024]
    unsigned short* gB = actB;
    k_gemm<0, 0, 0><<<dim3(18, 8), 256, 0, stream>>>(ww0b, col4, wb0, gA, 1600, 1024, 1024);

    // ---- 3 x conv3x3 1024->1024 at 48x48
    unsigned short* gs = gA;
    unsigned short* gd = gB;
    for (int i = 0; i < 3; ++i) {
        k_wcvt<1024, 9><<<1024, 256, 0, stream>>>(ww_mid + (size_t)i * 9437184, wmb, 1024, 9216);
        k_im2col3<1024><<<2304, 256, 0, stream>>>(gs, colF, 48, 48, 9216);
        k_gemm<0, 0, 0><<<dim3(18, 8), 256, 0, stream>>>(wmb, colF, wb_mid + i * 1024, gd, 9216, 1024, 1024);
        unsigned short* t = gs; gs = gd; gd = t;
    }
    // gs == gB (final g)

    // ---- two 1x1 convs (GEMMs)
    k_gemm<0, 0, 0><<<dim3(18, 49), 256, 0, stream>>>(ww1b, gs, wb1, g1, 1024, 6272, 6272);
    k_gemm<1, 1, 1><<<dim3(18, 98), 256, 0, stream>>>(ww2, g1, wb2, WmT, 6272, 12544, 12544);

    // ---- per-pixel solve
    k_solve<<<2304, 256, 0, stream>>>(WmT, design, input, out);
}